// Round 1
// baseline (206.420 us; speedup 1.0000x reference)
//
#include <hip/hip_runtime.h>
#include <hip/hip_bf16.h>

#define NN 8192
#define IN_F 256
#define OF 128

typedef __bf16 bf16x8 __attribute__((ext_vector_type(8)));
typedef float  f32x4  __attribute__((ext_vector_type(4)));

// ---------------------------------------------------------------------------
// Kernel A: h = X @ W  (f32, LDS-staged W), then emit:
//   Ht  : bf16 [OF][NN]  (transposed h, for contiguous MFMA B-fragments)
//   f_src[i] = h[i] . a[:OF],  f_dst[i] = h[i] . a[OF:]
// 256 blocks x 256 threads, 32 rows/block. W (128 KiB f32) lives in LDS.
// ---------------------------------------------------------------------------
__global__ __launch_bounds__(256) void gat_prep(
    const float* __restrict__ X, const float* __restrict__ W,
    const float* __restrict__ a, __bf16* __restrict__ Ht,
    float* __restrict__ f_src, float* __restrict__ f_dst)
{
    __shared__ float Wlds[IN_F * OF];   // 128 KiB
    __shared__ float red_s[32][8];
    __shared__ float red_d[32][8];

    const int t = threadIdx.x;
    // cooperative load of W into LDS (linear copy, row-major [256][128])
    {
        const f32x4* Wv = (const f32x4*)W;
        f32x4*       Wl = (f32x4*)Wlds;
        #pragma unroll
        for (int c = 0; c < 32; ++c) Wl[c * 256 + t] = Wv[c * 256 + t];
    }
    __syncthreads();

    const int row = t & 31;       // 32 rows/block
    const int sub = t >> 5;       // 8 col-groups of 16 cols
    const int i   = blockIdx.x * 32 + row;

    f32x4 acc[4] = {};            // 16 output cols
    const float* xrow = X + (size_t)i * IN_F;

    #pragma unroll 4
    for (int kk = 0; kk < IN_F; kk += 4) {
        f32x4 xv = *(const f32x4*)(xrow + kk);
        #pragma unroll
        for (int e = 0; e < 4; ++e) {
            const f32x4* wr = (const f32x4*)(Wlds + (kk + e) * OF + sub * 16);
            float xs = xv[e];
            #pragma unroll
            for (int c4 = 0; c4 < 4; ++c4) acc[c4] += xs * wr[c4];
        }
    }

    // attention-vector dots + transposed bf16 store
    float ps = 0.f, pd = 0.f;
    #pragma unroll
    for (int c4 = 0; c4 < 4; ++c4) {
        #pragma unroll
        for (int e = 0; e < 4; ++e) {
            float v = acc[c4][e];
            int   c = sub * 16 + c4 * 4 + e;
            ps += v * a[c];
            pd += v * a[OF + c];
            Ht[(size_t)c * NN + i] = (__bf16)v;
        }
    }
    red_s[row][sub] = ps;
    red_d[row][sub] = pd;
    __syncthreads();
    if (t < 32) {
        float s = 0.f;
        #pragma unroll
        for (int s8 = 0; s8 < 8; ++s8) s += red_s[t][s8];
        f_src[blockIdx.x * 32 + t] = s;
    } else if (t < 64) {
        const int r2 = t - 32;
        float s = 0.f;
        #pragma unroll
        for (int s8 = 0; s8 < 8; ++s8) s += red_d[r2][s8];
        f_dst[blockIdx.x * 32 + r2] = s;
    }
}

// ---------------------------------------------------------------------------
// Kernel B: flash-GAT. 512 blocks x 512 threads (8 waves), 16 rows/block.
// Waves split the j (neighbor) dimension; each wave accumulates a private
// 16x128 f32 tile + per-row denom. No max-subtraction needed: e <= ~10 so
// exp(e) is safely inside f32 range -> plain exp accumulation == softmax.
// MFMA 16x16x32 bf16:
//   A (P tile 16x32): lane: row = lane&15, k = 8*(lane>>4)+e
//   B (H tile 32x16): lane: col = lane&15, k = 8*(lane>>4)+e  (from Ht)
//   D: col = lane&15, row = 4*(lane>>4)+reg
// ---------------------------------------------------------------------------
__global__ __launch_bounds__(512) void gat_flash(
    const int* __restrict__ adj, const __bf16* __restrict__ Ht,
    const float* __restrict__ f_src, const float* __restrict__ f_dst,
    float* __restrict__ out)
{
    __shared__ float red[8][16][OF];   // 64 KiB
    __shared__ float rden[8][16];

    const int tid  = threadIdx.x;
    const int wave = tid >> 6;
    const int lane = tid & 63;
    const int r    = lane & 15;
    const int g    = lane >> 4;
    const int rowbase = blockIdx.x * 16;
    const int i    = rowbase + r;

    const float fsrc_i = f_src[i];
    const int* adjrow  = adj + (size_t)i * NN;

    f32x4 acc[8] = {};
    float psum = 0.f;

    for (int tile = wave; tile < NN / 32; tile += 8) {
        const int kbase = tile * 32 + g * 8;

        const int4  a0 = *(const int4*)(adjrow + kbase);
        const int4  a1 = *(const int4*)(adjrow + kbase + 4);
        const f32x4 fd0 = *(const f32x4*)(f_dst + kbase);
        const f32x4 fd1 = *(const f32x4*)(f_dst + kbase + 4);

        const int   av[8]  = {a0.x, a0.y, a0.z, a0.w, a1.x, a1.y, a1.z, a1.w};
        const float fdv[8] = {fd0[0], fd0[1], fd0[2], fd0[3],
                              fd1[0], fd1[1], fd1[2], fd1[3]};
        float p[8];
        bf16x8 af;
        #pragma unroll
        for (int e = 0; e < 8; ++e) {
            float s = fsrc_i + fdv[e];
            s = s > 0.f ? s : 0.2f * s;          // leaky_relu
            float pe = (av[e] != 0) ? __expf(s) : 0.f;
            p[e] = pe;
            af[e] = (__bf16)pe;
        }
        psum += ((p[0] + p[1]) + (p[2] + p[3])) + ((p[4] + p[5]) + (p[6] + p[7]));

        #pragma unroll
        for (int nt = 0; nt < 8; ++nt) {
            const bf16x8 bf = *(const bf16x8*)(Ht + (size_t)(nt * 16 + r) * NN + kbase);
            acc[nt] = __builtin_amdgcn_mfma_f32_16x16x32_bf16(af, bf, acc[nt], 0, 0, 0);
        }
    }

    // denom: reduce psum over the 4 k-groups (lanes r, r^16, r^32, r^48)
    psum += __shfl_xor(psum, 16, 64);
    psum += __shfl_xor(psum, 32, 64);

    #pragma unroll
    for (int nt = 0; nt < 8; ++nt) {
        #pragma unroll
        for (int q = 0; q < 4; ++q)
            red[wave][g * 4 + q][nt * 16 + r] = acc[nt][q];
    }
    if (lane < 16) rden[wave][lane] = psum;
    __syncthreads();

    // epilogue: 512 threads x 4 outputs = 16x128 tile
    const int orow = tid >> 5;     // 0..15
    const int cg   = tid & 31;     // 4-col group
    f32x4 v = {};
    float den = 0.f;
    #pragma unroll
    for (int w = 0; w < 8; ++w) {
        v   += *(const f32x4*)&red[w][orow][cg * 4];
        den += rden[w][orow];
    }
    const float inv = 1.0f / den;
    f32x4 o = v * inv;
    #pragma unroll
    for (int e = 0; e < 4; ++e) o[e] = fmaxf(o[e], 0.f);
    *(f32x4*)(out + (size_t)(rowbase + orow) * OF + cg * 4) = o;
}

extern "C" void kernel_launch(void* const* d_in, const int* in_sizes, int n_in,
                              void* d_out, int out_size, void* d_ws, size_t ws_size,
                              hipStream_t stream) {
    const float* X   = (const float*)d_in[0];
    const int*   adj = (const int*)d_in[1];
    const float* W   = (const float*)d_in[2];
    const float* a   = (const float*)d_in[3];
    float* out = (float*)d_out;

    __bf16* Ht    = (__bf16*)d_ws;                                  // 2 MiB
    float*  f_src = (float*)((char*)d_ws + (size_t)OF * NN * sizeof(__bf16));
    float*  f_dst = f_src + NN;

    gat_prep<<<NN / 32, 256, 0, stream>>>(X, W, a, Ht, f_src, f_dst);
    gat_flash<<<NN / 16, 512, 0, stream>>>(adj, Ht, f_src, f_dst, out);
}